// Round 1
// baseline (634.041 us; speedup 1.0000x reference)
//
#include <hip/hip_runtime.h>

#define BB 8
#define SS 1024
#define HH 768
#define EE 9
#define DD 64
#define NCOL (EE * 2 * DD)  // 1152

__device__ __forceinline__ float b2f(unsigned short u) {
    unsigned int x = ((unsigned int)u) << 16;
    return __uint_as_float(x);
}
__device__ __forceinline__ unsigned short f2b(float f) {
    unsigned int x = __float_as_uint(f);
    unsigned int r = (x + 0x7fffu + ((x >> 16) & 1u)) >> 16;
    return (unsigned short)r;
}

// Kernel 1: C = lhs @ W^T + b, RoPE, write q/k bf16 to ws in [b*E+e][s][d].
__global__ __launch_bounds__(256) void dense_rope_kernel(
    const float* __restrict__ lhs,   // [B*S][H]
    const float* __restrict__ W,     // [1152][H]
    const float* __restrict__ bias,  // [1152]
    unsigned short* __restrict__ q_ws,
    unsigned short* __restrict__ k_ws) {
    __shared__ float As[16][68];  // [k][m], padded
    __shared__ float Bs[16][68];  // [k][j], padded
    __shared__ float Cs[64][65];  // [m][j] result tile for RoPE partner access

    const int t = threadIdx.x;
    const int tx = t & 15, ty = t >> 4;
    const int m0 = blockIdx.y * 64;
    const int j0 = blockIdx.x * 64;

    const int r = t >> 2;        // 0..63 row within tile
    const int cc = (t & 3) * 4;  // 0,4,8,12 col within 16-wide K slab

    float acc[4][4] = {};

    for (int kt = 0; kt < HH / 16; ++kt) {
        const int k0 = kt * 16;
        float4 av = *(const float4*)&lhs[(size_t)(m0 + r) * HH + k0 + cc];
        float4 bv = *(const float4*)&W[(size_t)(j0 + r) * HH + k0 + cc];
        __syncthreads();  // previous tile consumed
        As[cc + 0][r] = av.x; As[cc + 1][r] = av.y;
        As[cc + 2][r] = av.z; As[cc + 3][r] = av.w;
        Bs[cc + 0][r] = bv.x; Bs[cc + 1][r] = bv.y;
        Bs[cc + 2][r] = bv.z; Bs[cc + 3][r] = bv.w;
        __syncthreads();
#pragma unroll
        for (int kk = 0; kk < 16; ++kk) {
            float4 a = *(const float4*)&As[kk][ty * 4];
            float4 b = *(const float4*)&Bs[kk][tx * 4];
            float aa[4] = {a.x, a.y, a.z, a.w};
            float bb[4] = {b.x, b.y, b.z, b.w};
#pragma unroll
            for (int i = 0; i < 4; ++i)
#pragma unroll
                for (int j = 0; j < 4; ++j) acc[i][j] += aa[i] * bb[j];
        }
    }

    // bias + stash in LDS (each thread owns its 4x4, no hazard before sync)
#pragma unroll
    for (int i = 0; i < 4; ++i)
#pragma unroll
        for (int jj = 0; jj < 4; ++jj)
            Cs[ty * 4 + i][tx * 4 + jj] = acc[i][jj] + bias[j0 + tx * 4 + jj];
    __syncthreads();

    // RoPE + scatter to q/k workspace (bf16)
    const float LOG2_1E4_OVER_32 = 0.4152410118609203f;  // log2(10000)/32
#pragma unroll
    for (int i = 0; i < 4; ++i) {
        const int m = m0 + ty * 4 + i;
        const int b_idx = m >> 10;
        const int s = m & (SS - 1);
#pragma unroll
        for (int jj = 0; jj < 4; ++jj) {
            const int lj = tx * 4 + jj;
            const int j = j0 + lj;
            const int d = j & 63;
            const int g = j >> 6;
            const int e = g >> 1;
            const int isK = g & 1;
            float val = Cs[ty * 4 + i][lj];
            float rot = (d < 32) ? -Cs[ty * 4 + i][lj + 32]
                                 : Cs[ty * 4 + i][lj - 32];
            float inv = exp2f(-(float)(d >> 1) * LOG2_1E4_OVER_32);
            float ang = (float)s * inv;
            float sv, cv;
            __sincosf(ang, &sv, &cv);
            float res = val * cv + rot * sv;
            size_t off = ((size_t)(b_idx * EE + e) * SS + s) * DD + d;
            if (isK) k_ws[off] = f2b(res);
            else     q_ws[off] = f2b(res);
        }
    }
}

// Kernel 2: logits[z][m][n] = dot(q[z][m], k[z][n]) / 8, masked.
__global__ __launch_bounds__(256) void logits_kernel(
    const unsigned short* __restrict__ q_ws,
    const unsigned short* __restrict__ k_ws,
    const float* __restrict__ mask,  // [B][S]
    float* __restrict__ out) {       // [B*E][S][S]
    __shared__ float Qs[64][68];  // [d][m]
    __shared__ float Ks[64][68];  // [d][n]

    const int t = threadIdx.x;
    const int tx = t & 15, ty = t >> 4;
    const int n0 = blockIdx.x * 64;
    const int m0 = blockIdx.y * 64;
    const int z = blockIdx.z;  // b*E + e
    const int b_idx = z / EE;

    const unsigned short* qb = q_ws + ((size_t)z * SS + m0) * DD;
    const unsigned short* kb = k_ws + ((size_t)z * SS + n0) * DD;

#pragma unroll
    for (int ii = 0; ii < 4; ++ii) {
        int idx = t + ii * 256;   // 0..1023 ushort4 chunks
        int rr = idx >> 4;        // row 0..63
        int cc = (idx & 15) * 4;  // col 0..60
        ushort4 qv = ((const ushort4*)qb)[idx];
        ushort4 kv = ((const ushort4*)kb)[idx];
        Qs[cc + 0][rr] = b2f(qv.x); Qs[cc + 1][rr] = b2f(qv.y);
        Qs[cc + 2][rr] = b2f(qv.z); Qs[cc + 3][rr] = b2f(qv.w);
        Ks[cc + 0][rr] = b2f(kv.x); Ks[cc + 1][rr] = b2f(kv.y);
        Ks[cc + 2][rr] = b2f(kv.z); Ks[cc + 3][rr] = b2f(kv.w);
    }
    __syncthreads();

    float acc[4][4] = {};
#pragma unroll
    for (int kk = 0; kk < 64; ++kk) {
        float4 a = *(const float4*)&Qs[kk][ty * 4];
        float4 b = *(const float4*)&Ks[kk][tx * 4];
        float aa[4] = {a.x, a.y, a.z, a.w};
        float bb[4] = {b.x, b.y, b.z, b.w};
#pragma unroll
        for (int i = 0; i < 4; ++i)
#pragma unroll
            for (int j = 0; j < 4; ++j) acc[i][j] += aa[i] * bb[j];
    }

    float4 pad4 = *(const float4*)&mask[(size_t)b_idx * SS + n0 + tx * 4];
    float pads[4] = {pad4.x, pad4.y, pad4.z, pad4.w};

#pragma unroll
    for (int i = 0; i < 4; ++i) {
        const int m = m0 + ty * 4 + i;
        float4 o;
        float ov[4];
#pragma unroll
        for (int jj = 0; jj < 4; ++jj) {
            const int n = n0 + tx * 4 + jj;
            float v = acc[i][jj] * 0.125f;
            float p = pads[jj];
            v = v * p - (1.0f - p) * 10000.0f;
            if (n < m) v -= 10000.0f;
            ov[jj] = v;
        }
        o.x = ov[0]; o.y = ov[1]; o.z = ov[2]; o.w = ov[3];
        *(float4*)&out[((size_t)z * SS + m) * SS + n0 + tx * 4] = o;
    }
}

extern "C" void kernel_launch(void* const* d_in, const int* in_sizes, int n_in,
                              void* d_out, int out_size, void* d_ws, size_t ws_size,
                              hipStream_t stream) {
    const float* lhs  = (const float*)d_in[0];  // [8][1024][768]
    const float* mask = (const float*)d_in[1];  // [8][1024]
    const float* W    = (const float*)d_in[2];  // [1152][768]
    const float* bias = (const float*)d_in[3];  // [1152]
    float* out = (float*)d_out;                 // [8][9][1024][1024]

    unsigned short* q_ws = (unsigned short*)d_ws;                 // B*E*S*D bf16
    unsigned short* k_ws = q_ws + (size_t)BB * EE * SS * DD;      // 4,718,592 each

    dim3 g1(NCOL / 64, (BB * SS) / 64);  // 18 x 128
    dense_rope_kernel<<<g1, 256, 0, stream>>>(lhs, W, bias, q_ws, k_ws);

    dim3 g2(SS / 64, SS / 64, BB * EE);  // 16 x 16 x 72
    logits_kernel<<<g2, 256, 0, stream>>>(q_ws, k_ws, mask, out);
}

// Round 2
// 399.210 us; speedup vs baseline: 1.5882x; 1.5882x over previous
//
#include <hip/hip_runtime.h>

#define BB 8
#define SS 1024
#define HH 768
#define EE 9
#define DD 64
#define NCOL (EE * 2 * DD)  // 1152

typedef __bf16 bf16x8 __attribute__((ext_vector_type(8)));
typedef float f32x4 __attribute__((ext_vector_type(4)));

__device__ __forceinline__ unsigned short f2b(float f) {
    unsigned int x = __float_as_uint(f);
    unsigned int r = (x + 0x7fffu + ((x >> 16) & 1u)) >> 16;
    return (unsigned short)r;
}

// ---------------------------------------------------------------------------
// Kernel 1: C = lhs @ W^T + bias, RoPE, write q/k bf16 to ws [b*E+e][s][d].
// 128x128 block tile, BK=32, 4 waves in 2x2. Each wave: 64x64 via 4x4 of
// 16x16x32 bf16 MFMA. Wave N-span = 64 = exactly one (e, q/k) group, so the
// rotate-half partner (d +/- 32) is acc tile nt +/- 2, same lane & reg.
// ---------------------------------------------------------------------------
#define LDA1 40  // 32 + 8 pad (ushort elems); row stride 80 B, 16B-aligned
__global__ __launch_bounds__(256) void dense_rope_mfma(
    const float* __restrict__ lhs,   // [B*S][H]
    const float* __restrict__ W,     // [1152][H]
    const float* __restrict__ bias,  // [1152]
    unsigned short* __restrict__ q_ws,
    unsigned short* __restrict__ k_ws) {
    __shared__ unsigned short As[128 * LDA1];
    __shared__ unsigned short Bs[128 * LDA1];

    const int t = threadIdx.x;
    const int lane = t & 63, wave = t >> 6;
    const int quad = lane >> 4, lr = lane & 15;
    const int wm = wave >> 1, wn = wave & 1;
    const int j0 = blockIdx.x * 128;  // x-major over N: consecutive blocks reuse A in L2
    const int m0 = blockIdx.y * 128;

    f32x4 acc[4][4] = {};

    for (int kt = 0; kt < HH / 32; ++kt) {
        const int k0 = kt * 32;
        float4 av[4], bv[4];
#pragma unroll
        for (int i = 0; i < 4; ++i) {
            int idx = t + i * 256;          // 1024 float4 chunks per 128x32 tile
            int row = idx >> 3, c4 = (idx & 7) * 4;
            av[i] = *(const float4*)&lhs[(size_t)(m0 + row) * HH + k0 + c4];
            bv[i] = *(const float4*)&W[(size_t)(j0 + row) * HH + k0 + c4];
        }
        __syncthreads();  // previous tile's LDS fully consumed
#pragma unroll
        for (int i = 0; i < 4; ++i) {
            int idx = t + i * 256;
            int row = idx >> 3, c4 = (idx & 7) * 4;
            ushort4 a4 = {f2b(av[i].x), f2b(av[i].y), f2b(av[i].z), f2b(av[i].w)};
            ushort4 b4 = {f2b(bv[i].x), f2b(bv[i].y), f2b(bv[i].z), f2b(bv[i].w)};
            *(ushort4*)&As[row * LDA1 + c4] = a4;
            *(ushort4*)&Bs[row * LDA1 + c4] = b4;
        }
        __syncthreads();

        bf16x8 af[4], bf[4];
#pragma unroll
        for (int mt = 0; mt < 4; ++mt)
            af[mt] = *(const bf16x8*)&As[(wm * 64 + mt * 16 + lr) * LDA1 + quad * 8];
#pragma unroll
        for (int nt = 0; nt < 4; ++nt)
            bf[nt] = *(const bf16x8*)&Bs[(wn * 64 + nt * 16 + lr) * LDA1 + quad * 8];
#pragma unroll
        for (int mt = 0; mt < 4; ++mt)
#pragma unroll
            for (int nt = 0; nt < 4; ++nt)
                acc[mt][nt] = __builtin_amdgcn_mfma_f32_16x16x32_bf16(
                    af[mt], bf[nt], acc[mt][nt], 0, 0, 0);
    }

    // Epilogue: bias + RoPE entirely in registers, store bf16.
    const int gcol0 = j0 + wn * 64;       // aligned 64-col group
    const int g = gcol0 >> 6;
    const int e = g >> 1;
    unsigned short* dst = (g & 1) ? k_ws : q_ws;
    const int b_idx = m0 >> 10;           // 128 | 1024, uniform per block
    const size_t zbase = (size_t)(b_idx * EE + e) * SS;
    const float L2_1E4_D32 = 0.4152410118609203f;  // log2(10000)/32

    float bb[4], invf[4];
#pragma unroll
    for (int nt = 0; nt < 4; ++nt) {
        bb[nt] = bias[gcol0 + nt * 16 + lr];
        int half = (nt * 16 + lr) >> 1;
        invf[nt] = exp2f(-(float)half * L2_1E4_D32);
    }
    const int s0 = (m0 & (SS - 1)) + wm * 64;
#pragma unroll
    for (int mt = 0; mt < 4; ++mt) {
#pragma unroll
        for (int reg = 0; reg < 4; ++reg) {
            const int s = s0 + mt * 16 + quad * 4 + reg;
            float c[4];
#pragma unroll
            for (int nt = 0; nt < 4; ++nt) c[nt] = acc[mt][nt][reg] + bb[nt];
#pragma unroll
            for (int nt = 0; nt < 4; ++nt) {
                float rot = (nt < 2) ? -c[nt + 2] : c[nt - 2];
                float ang = (float)s * invf[nt];
                float sv, cv;
                __sincosf(ang, &sv, &cv);
                const int d = nt * 16 + lr;
                dst[(zbase + s) * DD + d] = f2b(c[nt] * cv + rot * sv);
            }
        }
    }
}

// ---------------------------------------------------------------------------
// Kernel 2: logits[z][m][n] = dot(q[z][m], k[z][n]) / 8, pad + causal mask.
// 128x128 tile per block, K=64 staged once (2 MFMA k-steps), direct stores.
// ---------------------------------------------------------------------------
#define LDA2 72  // 64 + 8 pad; row stride 144 B, 16B-aligned
__global__ __launch_bounds__(256) void logits_mfma(
    const unsigned short* __restrict__ q_ws,
    const unsigned short* __restrict__ k_ws,
    const float* __restrict__ mask,  // [B][S]
    float* __restrict__ out) {       // [B*E][S][S]
    __shared__ unsigned short Qs[128 * LDA2];
    __shared__ unsigned short Ks[128 * LDA2];

    const int t = threadIdx.x;
    const int lane = t & 63, wave = t >> 6;
    const int quad = lane >> 4, lr = lane & 15;
    const int wm = wave >> 1, wn = wave & 1;
    const int n0 = blockIdx.x * 128;
    const int m0 = blockIdx.y * 128;
    const int z = blockIdx.z;        // b*E + e
    const int b_idx = z / EE;

    const uint4* qsrc = (const uint4*)(q_ws + ((size_t)z * SS + m0) * DD);
    const uint4* ksrc = (const uint4*)(k_ws + ((size_t)z * SS + n0) * DD);
#pragma unroll
    for (int i = 0; i < 4; ++i) {
        int idx = t + i * 256;       // 1024 16B chunks per 128x64 bf16 tile
        int row = idx >> 3, c8 = (idx & 7) * 8;
        uint4 qv = qsrc[idx];
        uint4 kv = ksrc[idx];
        *(uint4*)&Qs[row * LDA2 + c8] = qv;
        *(uint4*)&Ks[row * LDA2 + c8] = kv;
    }
    __syncthreads();

    f32x4 acc[4][4] = {};
#pragma unroll
    for (int ks = 0; ks < DD; ks += 32) {
        bf16x8 af[4], bf[4];
#pragma unroll
        for (int mt = 0; mt < 4; ++mt)
            af[mt] = *(const bf16x8*)&Qs[(wm * 64 + mt * 16 + lr) * LDA2 + ks + quad * 8];
#pragma unroll
        for (int nt = 0; nt < 4; ++nt)
            bf[nt] = *(const bf16x8*)&Ks[(wn * 64 + nt * 16 + lr) * LDA2 + ks + quad * 8];
#pragma unroll
        for (int mt = 0; mt < 4; ++mt)
#pragma unroll
            for (int nt = 0; nt < 4; ++nt)
                acc[mt][nt] = __builtin_amdgcn_mfma_f32_16x16x32_bf16(
                    af[mt], bf[nt], acc[mt][nt], 0, 0, 0);
    }

    float p[4];
#pragma unroll
    for (int nt = 0; nt < 4; ++nt)
        p[nt] = mask[b_idx * SS + n0 + wn * 64 + nt * 16 + lr];

    float* outz = out + (size_t)z * SS * SS;
#pragma unroll
    for (int mt = 0; mt < 4; ++mt) {
#pragma unroll
        for (int reg = 0; reg < 4; ++reg) {
            const int m = m0 + wm * 64 + mt * 16 + quad * 4 + reg;
#pragma unroll
            for (int nt = 0; nt < 4; ++nt) {
                const int n = n0 + wn * 64 + nt * 16 + lr;
                float v = acc[mt][nt][reg] * 0.125f;
                v = v * p[nt] - (1.0f - p[nt]) * 10000.0f;
                if (n < m) v -= 10000.0f;
                outz[(size_t)m * SS + n] = v;
            }
        }
    }
}

extern "C" void kernel_launch(void* const* d_in, const int* in_sizes, int n_in,
                              void* d_out, int out_size, void* d_ws, size_t ws_size,
                              hipStream_t stream) {
    const float* lhs  = (const float*)d_in[0];  // [8][1024][768]
    const float* mask = (const float*)d_in[1];  // [8][1024]
    const float* W    = (const float*)d_in[2];  // [1152][768]
    const float* bias = (const float*)d_in[3];  // [1152]
    float* out = (float*)d_out;                 // [8][9][1024][1024]

    unsigned short* q_ws = (unsigned short*)d_ws;
    unsigned short* k_ws = q_ws + (size_t)BB * EE * SS * DD;  // 4,718,592 each

    dim3 g1(NCOL / 128, (BB * SS) / 128);  // 9 x 64
    dense_rope_mfma<<<g1, 256, 0, stream>>>(lhs, W, bias, q_ws, k_ws);

    dim3 g2(SS / 128, SS / 128, BB * EE);  // 8 x 8 x 72
    logits_mfma<<<g2, 256, 0, stream>>>(q_ws, k_ws, mask, out);
}